// Round 9
// baseline (115.337 us; speedup 1.0000x reference)
//
#include <hip/hip_runtime.h>
#include <hip/hip_bf16.h>

// Nav_64939905516231 (VIN value iteration), MI355X gfx950.
// B=64,H=W=64,dim_h=150,n_hat=8,n_act=4,K=10. fp32 in/out, maze int32.
// Collapses: r = conv5x5(m,W_eff)+b_eff (150ch folded); q_t = q0 + conv5x5(v,w).
// R31 = R30 (LDS-pipe attack) with the permlane butterflies via the REAL
// builtins. R30's inline asm ("+v"(a),"+v"(b) both = m) let the allocator
// coalesce a,b,m into ONE register -> in-place rotate, fmax returned the
// partner value (absmax 0.81). __builtin_amdgcn_permlane16/32_swap returns
// the {vdst,vsrc} pair with compiler-known semantics; fmax(pair) = xor-K max.
// __has_builtin guard falls back to __shfl_xor (ds path, known correct).
// Structure: (1) channel combine on VALU (no LDS); (2) 2-row sweeps -- tap
// rows lr-2..lr+3 read once for both rows (6 b128/row vs 10). LDS cyc/row
// ~180 -> ~80 on the CU's single LDS pipe (theory: 3x oversubscribed vs
// 4 SIMDs of VALU; occupancy 2->3 waves/SIMD bought nothing in R29).
// Lane: cq = lane>>4, p4 = (lane&15)*4; 768 thr = 12 waves, 3 waves/SIMD.
// 1 barrier/step, dbuf vbuf. ~44us ws fill + ~18us dispatch harness-fixed.

#define NHAT 8
#define DIMH 150
#define VI_WAVES 12

typedef float v2f __attribute__((ext_vector_type(2)));

// xor-16 / xor-32 butterflies on the VALU (gfx950 permlane*_swap builtins).
// swap(m,m) -> {rows 0,0,2,2} and {rows 1,1,3,3} (16) or {lo,lo},{hi,hi} (32);
// combining the pair gives the xor-K reduce in every lane.
__device__ __forceinline__ float xor16_max(float m) {
#if __has_builtin(__builtin_amdgcn_permlane16_swap)
  unsigned u = __float_as_uint(m);
  auto r = __builtin_amdgcn_permlane16_swap(u, u, false, false);
  return fmaxf(__uint_as_float(r[0]), __uint_as_float(r[1]));
#else
  return fmaxf(m, __shfl_xor(m, 16));
#endif
}
__device__ __forceinline__ float xor32_max(float m) {
#if __has_builtin(__builtin_amdgcn_permlane32_swap)
  unsigned u = __float_as_uint(m);
  auto r = __builtin_amdgcn_permlane32_swap(u, u, false, false);
  return fmaxf(__uint_as_float(r[0]), __uint_as_float(r[1]));
#else
  return fmaxf(m, __shfl_xor(m, 32));
#endif
}
__device__ __forceinline__ float xor16_add(float m) {
#if __has_builtin(__builtin_amdgcn_permlane16_swap)
  unsigned u = __float_as_uint(m);
  auto r = __builtin_amdgcn_permlane16_swap(u, u, false, false);
  return __uint_as_float(r[0]) + __uint_as_float(r[1]);
#else
  return m + __shfl_xor(m, 16);
#endif
}
__device__ __forceinline__ float xor32_add(float m) {
#if __has_builtin(__builtin_amdgcn_permlane32_swap)
  unsigned u = __float_as_uint(m);
  auto r = __builtin_amdgcn_permlane32_swap(u, u, false, false);
  return __uint_as_float(r[0]) + __uint_as_float(r[1]);
#else
  return m + __shfl_xor(m, 32);
#endif
}

// ------- rq: prep (parallel) + r = table-conv(maze) + q0 -------
// q0 layout: q0g[(((b*64+gy)*4 + j)*64 + gx)*2] v2f = ch pair (2j,2j+1).
__global__ __launch_bounds__(512) void rq_kernel(
    const int* __restrict__ maze, const float* __restrict__ emb,
    const float* __restrict__ encode_w, const float* __restrict__ encode_b,
    const float* __restrict__ r_w, const float* __restrict__ q_w,
    float* __restrict__ q0g) {
  __shared__ float wpart[5][50];
  __shared__ float bpart[152];
  __shared__ float weff[2][25];
  __shared__ float Ts[4][25];
  __shared__ float bsh;
  __shared__ v2f qw2[25][4];
  __shared__ unsigned char mzt[24][68];
  __shared__ float rt[20][68];

  int tid = threadIdx.x;
  int b = blockIdx.y, A0 = blockIdx.x * 16;

  // P0: weight stage + W_eff partials + maze tile
  if (tid < 100) {
    int k = tid >> 2, j = tid & 3;
    qw2[k][j] = (v2f){q_w[(2 * j) * 25 + k], q_w[(2 * j + 1) * 25 + k]};
  }
  if (tid >= 256 && tid < 506) {
    int t2 = tid - 256;
    int chunk = t2 / 50, ik = t2 % 50;
    int i = ik / 25, k = ik % 25;
    int c0 = chunk * 30;
    float s = 0.f;
    for (int c = c0; c < c0 + 30; ++c)
      s += r_w[c] * encode_w[c * 50 + i * 25 + k];
    wpart[chunk][ik] = s;
  }
  if (tid >= 100 && tid < 250) {
    int c = tid - 100;
    bpart[c] = r_w[c] * encode_b[c];
  }
  for (int i = tid; i < 24 * 68; i += 512) {
    int mr = i / 68, mc = i % 68;
    int gy = A0 - 4 + mr, gx = mc - 2;
    unsigned char v = 3;
    if (gy >= 0 && gy < 64 && gx >= 0 && gx < 64)
      v = (unsigned char)maze[(b * 64 + gy) * 64 + gx];
    mzt[mr][mc] = v;
  }
  __syncthreads();
  // P1: reduce
  if (tid < 50) {
    float s = 0.f;
#pragma unroll
    for (int ch = 0; ch < 5; ++ch) s += wpart[ch][tid];
    weff[tid / 25][tid % 25] = s;
  }
  if (tid == 50) {
    float s = 0.f;
    for (int c = 0; c < 150; ++c) s += bpart[c];
    bsh = s;
  }
  __syncthreads();
  // P2: T table
  if (tid < 100) {
    int val = tid / 25, k = tid % 25;
    float t = 0.f;
    if (val < 3) t = weff[0][k] * emb[val * 2] + weff[1][k] * emb[val * 2 + 1];
    Ts[val][k] = t;  // row 3 == 0 (padding sentinel)
  }
  __syncthreads();
  // P3: r tile rows [A0-2, A0+18)
  for (int i = tid; i < 20 * 68; i += 512) {
    int rr = i / 68, cc = i % 68;
    int gy = A0 - 2 + rr, gx = cc - 2;
    float v = 0.f;
    if (gy >= 0 && gy < 64 && gx >= 0 && gx < 64) {
      v = bsh;
#pragma unroll
      for (int ky = 0; ky < 5; ++ky)
#pragma unroll
        for (int kx = 0; kx < 5; ++kx)
          v += Ts[mzt[rr + ky][cc - 2 + kx]][ky * 5 + kx];
    }
    rt[rr][cc] = v;
  }
  __syncthreads();
  // P4: q0 on owned 16 rows -> [b][gy][chpair][gx] v2f
  for (int i = tid; i < 16 * 64; i += 512) {
    int ly = i >> 6, gx = i & 63;
    int gy = A0 + ly;
    v2f acc[4];
#pragma unroll
    for (int j = 0; j < 4; ++j) acc[j] = (v2f){0.f, 0.f};
#pragma unroll
    for (int ky = 0; ky < 5; ++ky)
#pragma unroll
      for (int kx = 0; kx < 5; ++kx) {
        int k = ky * 5 + kx;
        float vv = rt[ly + ky][gx + kx];
        v2f vv2 = (v2f){vv, vv};
#pragma unroll
        for (int j = 0; j < 4; ++j) acc[j] += qw2[k][j] * vv2;
      }
#pragma unroll
    for (int j = 0; j < 4; ++j)
      *(v2f*)&q0g[(((size_t)(b * 64 + gy) * 4 + j) * 64 + gx) * 2] = acc[j];
  }
}

// =============== vi: 10 fused VI steps + projection =================
// Block (768 thr = 12 waves, 3/SIMD) owns rows [a0, a0+16); grid 256.
// Lane: cq = lane>>4 (channel pair), p4 = (lane&15)*4 (4-px group).
// Wave computes TWO rows (rb, rb+1) per sweep: tap rows lr-2..lr+3 read once
// (12 b128 per 2 rows). 8-ch max via VALU permlane butterflies; cq==0 writes
// combined rows. s,e always even -> no tail. 1 barrier/step, dbuf vbuf.
__global__ __launch_bounds__(768) void vi_kernel(
    const float* __restrict__ q0g, const float* __restrict__ w,
    const float* __restrict__ fc_w, float* __restrict__ out) {
  __shared__ __align__(16) float vbuf[2][60][68];  // 32.6 KB
  __shared__ v2f wl2[25][4];

  int tid = threadIdx.x;
  int b = blockIdx.y, a0 = blockIdx.x * 16;
  int wave = tid >> 6, lane = tid & 63;
  int cq = lane >> 4;        // channel pair 0..3
  int p4 = (lane & 15) * 4;  // px group start

  if (tid < 100) {
    int k = tid >> 2, j = tid & 3;
    wl2[k][j] = (v2f){w[(2 * j) * 25 + k], w[(2 * j + 1) * 25 + k]};
  }
  for (int i = tid; i < 2 * 60 * 68; i += 768) ((float*)vbuf)[i] = 0.f;
  __syncthreads();

  // this lane's 2 channels -> 25 v2f = 50 regs
  v2f wr[25];
#pragma unroll
  for (int k = 0; k < 25; ++k) wr[k] = wl2[k][cq];

  const float* q0b = q0g + (size_t)b * 64 * 4 * 64 * 2;
  int cur = 0;

  // v0 = max_c q0 on [a0-20, a0+36): full 8ch per lane, waves stride 12 rows
  {
    int s = max(0, a0 - 20), e = min(64, a0 + 36);
    int gx = lane;
    for (int r = s + wave; r < e; r += VI_WAVES) {
      v2f a0v = *(const v2f*)&q0b[(((size_t)r * 4 + 0) * 64 + gx) * 2];
      v2f a1v = *(const v2f*)&q0b[(((size_t)r * 4 + 1) * 64 + gx) * 2];
      v2f a2v = *(const v2f*)&q0b[(((size_t)r * 4 + 2) * 64 + gx) * 2];
      v2f a3v = *(const v2f*)&q0b[(((size_t)r * 4 + 3) * 64 + gx) * 2];
      float m = fmaxf(fmaxf(fmaxf(a0v.x, a0v.y), fmaxf(a1v.x, a1v.y)),
                      fmaxf(fmaxf(a2v.x, a2v.y), fmaxf(a3v.x, a3v.y)));
      vbuf[0][r - a0 + 22][gx + 2] = m;
    }
  }
  __syncthreads();

  for (int t = 1; t <= 9; ++t) {
    int hh = 2 * (10 - t);
    int s = max(0, a0 - hh), e = min(64, a0 + 16 + hh);  // both even
    for (int rb = s + 2 * wave; rb < e; rb += 2 * VI_WAVES) {
      int lr = rb - a0 + 22;
      const float4* qp0 =
          (const float4*)&q0b[(((size_t)rb * 4 + cq) * 64 + p4) * 2];
      const float4* qp1 =
          (const float4*)&q0b[(((size_t)(rb + 1) * 4 + cq) * 64 + p4) * 2];
      float4 q00 = qp0[0], q01 = qp0[1];
      float4 q10 = qp1[0], q11 = qp1[1];
      v2f A[4], Bv[4];
#pragma unroll
      for (int j = 0; j < 4; ++j) {
        A[j] = (v2f){0.f, 0.f};
        Bv[j] = (v2f){0.f, 0.f};
      }
#pragma unroll
      for (int jj = 0; jj < 6; ++jj) {
        const float* row = &vbuf[cur][lr - 2 + jj][p4];
        float4 fa = *(const float4*)row;
        float4 fb = *(const float4*)(row + 4);
        float f[8] = {fa.x, fa.y, fa.z, fa.w, fb.x, fb.y, fb.z, fb.w};
        if (jj < 5) {
#pragma unroll
          for (int kx = 0; kx < 5; ++kx) {
            v2f wk = wr[jj * 5 + kx];
#pragma unroll
            for (int j = 0; j < 4; ++j)
              A[j] += wk * (v2f){f[j + kx], f[j + kx]};
          }
        }
        if (jj > 0) {
#pragma unroll
          for (int kx = 0; kx < 5; ++kx) {
            v2f wk = wr[(jj - 1) * 5 + kx];
#pragma unroll
            for (int j = 0; j < 4; ++j)
              Bv[j] += wk * (v2f){f[j + kx], f[j + kx]};
          }
        }
      }
      // q0 added after the tap chain: L2 latency hides under FMAs
      A[0] += (v2f){q00.x, q00.y};  A[1] += (v2f){q00.z, q00.w};
      A[2] += (v2f){q01.x, q01.y};  A[3] += (v2f){q01.z, q01.w};
      Bv[0] += (v2f){q10.x, q10.y}; Bv[1] += (v2f){q10.z, q10.w};
      Bv[2] += (v2f){q11.x, q11.y}; Bv[3] += (v2f){q11.z, q11.w};
      float m0 = fmaxf(A[0].x, A[0].y), m1 = fmaxf(A[1].x, A[1].y);
      float m2 = fmaxf(A[2].x, A[2].y), m3 = fmaxf(A[3].x, A[3].y);
      float n0 = fmaxf(Bv[0].x, Bv[0].y), n1 = fmaxf(Bv[1].x, Bv[1].y);
      float n2 = fmaxf(Bv[2].x, Bv[2].y), n3 = fmaxf(Bv[3].x, Bv[3].y);
      // channel-pair combine on the VALU (no LDS traffic)
      m0 = xor32_max(xor16_max(m0)); m1 = xor32_max(xor16_max(m1));
      m2 = xor32_max(xor16_max(m2)); m3 = xor32_max(xor16_max(m3));
      n0 = xor32_max(xor16_max(n0)); n1 = xor32_max(xor16_max(n1));
      n2 = xor32_max(xor16_max(n2)); n3 = xor32_max(xor16_max(n3));
      if (cq == 0) {
        *(v2f*)&vbuf[cur ^ 1][lr][2 + p4] = (v2f){m0, m1};
        *(v2f*)&vbuf[cur ^ 1][lr][4 + p4] = (v2f){m2, m3};
        *(v2f*)&vbuf[cur ^ 1][lr + 1][2 + p4] = (v2f){n0, n1};
        *(v2f*)&vbuf[cur ^ 1][lr + 1][4 + p4] = (v2f){n2, n3};
      }
    }
    __syncthreads();
    cur ^= 1;
  }

  // final step t=10 + projection: waves 0-7 own row pair (a0+2*wave, +1)
  if (wave < 8) {
    int rb = a0 + 2 * wave;
    int lr = rb - a0 + 22;
    const float4* qp0 =
        (const float4*)&q0b[(((size_t)rb * 4 + cq) * 64 + p4) * 2];
    const float4* qp1 =
        (const float4*)&q0b[(((size_t)(rb + 1) * 4 + cq) * 64 + p4) * 2];
    float4 q00 = qp0[0], q01 = qp0[1];
    float4 q10 = qp1[0], q11 = qp1[1];
    v2f A[4], Bv[4];
#pragma unroll
    for (int j = 0; j < 4; ++j) {
      A[j] = (v2f){0.f, 0.f};
      Bv[j] = (v2f){0.f, 0.f};
    }
#pragma unroll
    for (int jj = 0; jj < 6; ++jj) {
      const float* row = &vbuf[cur][lr - 2 + jj][p4];
      float4 fa = *(const float4*)row;
      float4 fb = *(const float4*)(row + 4);
      float f[8] = {fa.x, fa.y, fa.z, fa.w, fb.x, fb.y, fb.z, fb.w};
      if (jj < 5) {
#pragma unroll
        for (int kx = 0; kx < 5; ++kx) {
          v2f wk = wr[jj * 5 + kx];
#pragma unroll
          for (int j = 0; j < 4; ++j)
            A[j] += wk * (v2f){f[j + kx], f[j + kx]};
        }
      }
      if (jj > 0) {
#pragma unroll
        for (int kx = 0; kx < 5; ++kx) {
          v2f wk = wr[(jj - 1) * 5 + kx];
#pragma unroll
          for (int j = 0; j < 4; ++j)
            Bv[j] += wk * (v2f){f[j + kx], f[j + kx]};
        }
      }
    }
    A[0] += (v2f){q00.x, q00.y};  A[1] += (v2f){q00.z, q00.w};
    A[2] += (v2f){q01.x, q01.y};  A[3] += (v2f){q01.z, q01.w};
    Bv[0] += (v2f){q10.x, q10.y}; Bv[1] += (v2f){q10.z, q10.w};
    Bv[2] += (v2f){q11.x, q11.y}; Bv[3] += (v2f){q11.z, q11.w};
    // projection: partial from this lane's 2 channels, VALU butterfly-sum
    v2f fcp2[4];
#pragma unroll
    for (int a = 0; a < 4; ++a)
      fcp2[a] = (v2f){fc_w[a * 8 + 2 * cq], fc_w[a * 8 + 2 * cq + 1]};
#pragma unroll
    for (int j = 0; j < 4; ++j) {
      float p0 = fcp2[0].x * A[j].x + fcp2[0].y * A[j].y;
      float p1 = fcp2[1].x * A[j].x + fcp2[1].y * A[j].y;
      float p2 = fcp2[2].x * A[j].x + fcp2[2].y * A[j].y;
      float p3 = fcp2[3].x * A[j].x + fcp2[3].y * A[j].y;
      p0 = xor32_add(xor16_add(p0));
      p1 = xor32_add(xor16_add(p1));
      p2 = xor32_add(xor16_add(p2));
      p3 = xor32_add(xor16_add(p3));
      if (cq == 0)
        *(float4*)&out[((size_t)((b * 64 + rb) * 64 + p4 + j)) * 4] =
            make_float4(p0, p1, p2, p3);
    }
#pragma unroll
    for (int j = 0; j < 4; ++j) {
      float p0 = fcp2[0].x * Bv[j].x + fcp2[0].y * Bv[j].y;
      float p1 = fcp2[1].x * Bv[j].x + fcp2[1].y * Bv[j].y;
      float p2 = fcp2[2].x * Bv[j].x + fcp2[2].y * Bv[j].y;
      float p3 = fcp2[3].x * Bv[j].x + fcp2[3].y * Bv[j].y;
      p0 = xor32_add(xor16_add(p0));
      p1 = xor32_add(xor16_add(p1));
      p2 = xor32_add(xor16_add(p2));
      p3 = xor32_add(xor16_add(p3));
      if (cq == 0)
        *(float4*)&out[((size_t)((b * 64 + rb + 1) * 64 + p4 + j)) * 4] =
            make_float4(p0, p1, p2, p3);
    }
  }
}

extern "C" void kernel_launch(void* const* d_in, const int* in_sizes, int n_in,
                              void* d_out, int out_size, void* d_ws, size_t ws_size,
                              hipStream_t stream) {
  const int* maze = (const int*)d_in[0];
  const float* emb = (const float*)d_in[1];
  const float* encode_w = (const float*)d_in[2];
  const float* encode_b = (const float*)d_in[3];
  const float* r_w = (const float*)d_in[4];
  const float* q_w = (const float*)d_in[5];
  const float* w = (const float*)d_in[6];
  const float* fc_w = (const float*)d_in[7];
  float* out = (float*)d_out;

  float* q0g = (float*)d_ws;  // 64*64*4*64*2 floats = 8 MB

  rq_kernel<<<dim3(4, 64), 512, 0, stream>>>(maze, emb, encode_w, encode_b,
                                             r_w, q_w, q0g);
  vi_kernel<<<dim3(4, 64), 768, 0, stream>>>(q0g, w, fc_w, out);
}